// Round 2
// baseline (21166.400 us; speedup 1.0000x reference)
//
#include <hip/hip_runtime.h>

// ---------------------------------------------------------------------------
// VariationalDropoutLSTM  (T=256, B=64, H=1024, L=2, fp32 in/out)
// Round 2: persistent scan kernel. fp16 split-weight (hi+lo) MFMA GEMMs.
//   gates = pre[t] + (h_{t-1} * mask_h[t]) @ Whh^T
//   pre   = input @ Wih^T + b_ih + b_hh   (input = x or h0_seq*mask_in)
// Scan: 256 WGs (1/CU, >256 VGPR, 0 LDS), Whh rows in registers, c in
// register, one tree grid-barrier per timestep, 64 steps per launch.
// ---------------------------------------------------------------------------

#define T_STEPS 256
#define BATCH   64
#define HID     1024
#define G4      4096
#define OUTSZ   (T_STEPS * BATCH * HID)   // 16777216
#define BH_     65536                      // BATCH*HID

typedef _Float16 half8 __attribute__((ext_vector_type(8)));
typedef _Float16 half4 __attribute__((ext_vector_type(4)));
typedef float    f32x4 __attribute__((ext_vector_type(4)));

__device__ __forceinline__ float sigm(float x) { return 1.0f / (1.0f + __expf(-x)); }

// ---------------------------------------------------------------------------
__global__ __launch_bounds__(256) void zero_ws(float* p, int n) {
    int i = blockIdx.x * 256 + threadIdx.x;
    if (i < n) p[i] = 0.0f;
}

// Split both weight tensors into fp16 hi/lo. 2*4096*1024 elems each layer-pair.
__global__ __launch_bounds__(256) void split_w(
    const float* __restrict__ wih, const float* __restrict__ whh,
    _Float16* __restrict__ wih_hi, _Float16* __restrict__ wih_lo,
    _Float16* __restrict__ whh_hi, _Float16* __restrict__ whh_lo)
{
    int i = blockIdx.x * 256 + threadIdx.x;
    {
        float4 a = ((const float4*)wih)[i];
        half4 h, l;
        h[0] = (_Float16)a.x; l[0] = (_Float16)(a.x - (float)h[0]);
        h[1] = (_Float16)a.y; l[1] = (_Float16)(a.y - (float)h[1]);
        h[2] = (_Float16)a.z; l[2] = (_Float16)(a.z - (float)h[2]);
        h[3] = (_Float16)a.w; l[3] = (_Float16)(a.w - (float)h[3]);
        ((half4*)wih_hi)[i] = h; ((half4*)wih_lo)[i] = l;
    }
    {
        float4 a = ((const float4*)whh)[i];
        half4 h, l;
        h[0] = (_Float16)a.x; l[0] = (_Float16)(a.x - (float)h[0]);
        h[1] = (_Float16)a.y; l[1] = (_Float16)(a.y - (float)h[1]);
        h[2] = (_Float16)a.z; l[2] = (_Float16)(a.z - (float)h[2]);
        h[3] = (_Float16)a.w; l[3] = (_Float16)(a.w - (float)h[3]);
        ((half4*)whh_hi)[i] = h; ((half4*)whh_lo)[i] = l;
    }
}

// ---------------------------------------------------------------------------
// pre_gemm: for chunk rows [row0, row0+4096): pre2[tt][gate][b][j] =
//   dot(A[row]*mask[row], W[g]) + bih[g]+bhh[g],  row = row0 + tt*64 + b,
//   g = gate*1024 + j.  128x128 tile, BK=32, 4 waves 2x2, 4x4 frags/wave.
__global__ __launch_bounds__(256) void pre_gemm(
    const float* __restrict__ A, const float* __restrict__ Amask, int row0,
    const _Float16* __restrict__ Bhi, const _Float16* __restrict__ Blo,
    const float* __restrict__ bih, const float* __restrict__ bhh,
    float* __restrict__ preOut)
{
    __shared__ _Float16 As [128][40];
    __shared__ _Float16 BsH[128][40];
    __shared__ _Float16 BsL[128][40];

    const int bm = blockIdx.x, bn = blockIdx.y;
    const int tid = threadIdx.x;
    const int wave = tid >> 6, lane = tid & 63;
    const int wm = wave & 1, wn = wave >> 1;
    const int lr = lane & 15, kq = lane >> 4;

    f32x4 acc[4][4] = {};

    const int mrow = tid >> 3;
    const int k4   = (tid & 7) * 4;
    const int nrow = tid >> 1;
    const int kb   = (tid & 1) * 16;

    for (int kk = 0; kk < 32; ++kk) {
        const int k0 = kk * 32;
        #pragma unroll
        for (int mi = 0; mi < 4; ++mi) {
            const int m = mrow + mi * 32;
            const size_t gofs = (size_t)(row0 + bm * 128 + m) * 1024 + k0 + k4;
            float4 av = *(const float4*)(A + gofs);
            if (Amask) {
                float4 mv = *(const float4*)(Amask + gofs);
                av.x *= mv.x; av.y *= mv.y; av.z *= mv.z; av.w *= mv.w;
            }
            half4 hv;
            hv[0] = (_Float16)av.x; hv[1] = (_Float16)av.y;
            hv[2] = (_Float16)av.z; hv[3] = (_Float16)av.w;
            *(half4*)&As[m][k4] = hv;
        }
        {
            const size_t gofs = (size_t)(bn * 128 + nrow) * 1024 + k0 + kb;
            half8 b0 = *(const half8*)(Bhi + gofs);
            half8 b1 = *(const half8*)(Bhi + gofs + 8);
            *(half8*)&BsH[nrow][kb]     = b0;
            *(half8*)&BsH[nrow][kb + 8] = b1;
            half8 c0 = *(const half8*)(Blo + gofs);
            half8 c1 = *(const half8*)(Blo + gofs + 8);
            *(half8*)&BsL[nrow][kb]     = c0;
            *(half8*)&BsL[nrow][kb + 8] = c1;
        }
        __syncthreads();

        half8 af[4], bh[4], bl[4];
        #pragma unroll
        for (int i = 0; i < 4; ++i)
            af[i] = *(const half8*)&As[wm * 64 + i * 16 + lr][kq * 8];
        #pragma unroll
        for (int j = 0; j < 4; ++j) {
            bh[j] = *(const half8*)&BsH[wn * 64 + j * 16 + lr][kq * 8];
            bl[j] = *(const half8*)&BsL[wn * 64 + j * 16 + lr][kq * 8];
        }
        #pragma unroll
        for (int i = 0; i < 4; ++i)
            #pragma unroll
            for (int j = 0; j < 4; ++j) {
                acc[i][j] = __builtin_amdgcn_mfma_f32_16x16x32_f16(af[i], bl[j], acc[i][j], 0, 0, 0);
                acc[i][j] = __builtin_amdgcn_mfma_f32_16x16x32_f16(af[i], bh[j], acc[i][j], 0, 0, 0);
            }
        __syncthreads();
    }

    // epilogue -> pre2[tt][gate][b][j]; D: col=lane&15, row=(lane>>4)*4+reg
    #pragma unroll
    for (int j4 = 0; j4 < 4; ++j4) {
        const int g = bn * 128 + wn * 64 + j4 * 16 + lr;
        const int gate = g >> 10, jc = g & 1023;
        const float bias = bih[g] + bhh[g];
        #pragma unroll
        for (int i = 0; i < 4; ++i) {
            const int rbase = bm * 128 + wm * 64 + i * 16 + kq * 4;
            #pragma unroll
            for (int r = 0; r < 4; ++r) {
                const int rloc = rbase + r;   // 0..4095 within chunk
                preOut[((size_t)(rloc >> 6) * 4 + gate) * BH_ + ((rloc & 63) << 10) + jc]
                    = acc[i][j4][r] + bias;
            }
        }
    }
}

// ---------------------------------------------------------------------------
// Persistent scan: 64 timesteps per launch. 256 WGs x 256 thr, 0 LDS,
// weights in VGPRs, c in a register, tree grid-barrier between steps.
// WG wg owns hidden cols j0=wg*4..+3 -> 16 Whh rows, LOCAL row = jj*4+gate.
// Wave w covers batch w*16..+15. Lane (lr,kq): MFMA D gives gates i,f,g,o
// in acc[0..3] for (jj=kq, b=w*16+lr) -> no LDS exchange needed.
__global__ __launch_bounds__(256, 1) void scan_chunk(
    const float*    __restrict__ pre2,    // [64][4][64][1024]
    const _Float16* __restrict__ WhhHi,   // [4096][1024]
    const _Float16* __restrict__ WhhLo,
    _Float16*       __restrict__ hm,      // [2][64][1024] ping-pong
    const float*    __restrict__ maskL,   // mask_h layer base [256][64][1024]
    float*          __restrict__ cbuf,    // [64][1024]
    float*          __restrict__ hA,      // h out base (full [256][64][1024])
    float*          __restrict__ hB,      // dup or null
    float*          __restrict__ cO,      // c out or null
    int tBase, int phaseBase,
    unsigned int*   __restrict__ bar)     // [8*32 group ctrs][release @256]
{
    const int wg   = blockIdx.x;
    const int j0   = wg << 2;
    const int tid  = threadIdx.x;
    const int w    = tid >> 6;
    const int lane = tid & 63;
    const int lr   = lane & 15;
    const int kq   = lane >> 4;

    // A-frag local row = lr ; global Whh row = gate*H + j0 + jj,
    // with gate = lr&3, jj = lr>>2  (local row = jj*4+gate)
    const int grow = (lr & 3) * HID + j0 + (lr >> 2);

    half8 wh[32], wl[32];
    {
        const _Float16* whp = WhhHi + (size_t)grow * HID + kq * 8;
        const _Float16* wlp = WhhLo + (size_t)grow * HID + kq * 8;
        #pragma unroll
        for (int kk = 0; kk < 32; ++kk) {
            wh[kk] = *(const half8*)(whp + kk * 32);
            wl[kk] = *(const half8*)(wlp + kk * 32);
        }
    }

    const int b  = (w << 4) + lr;
    const int j  = j0 + kq;
    const size_t bj = (size_t)b * HID + j;

    float creg = cbuf[bj];

    for (int tt = 0; tt < 64; ++tt) {
        const int t = tBase + tt;

        if (tt > 0) {
            // ---- grid barrier (phase = phaseBase + tt - 1, monotonic) ----
            __builtin_amdgcn_fence(__ATOMIC_RELEASE, "agent");
            __syncthreads();
            if (tid == 0) {
                const unsigned int phase = (unsigned int)(phaseBase + tt - 1);
                unsigned int old = atomicAdd(&bar[(wg & 7) * 32], 1u);
                if (old == 32u * (phase + 1u) - 1u)
                    atomicAdd(&bar[256], 1u);
                while (__hip_atomic_load(&bar[256], __ATOMIC_RELAXED,
                                         __HIP_MEMORY_SCOPE_AGENT) < 8u * (phase + 1u))
                    __builtin_amdgcn_s_sleep(2);
            }
            __syncthreads();
            __builtin_amdgcn_fence(__ATOMIC_ACQUIRE, "agent");
        }

        const _Float16* bp = hm + (size_t)(t & 1) * BH_ + ((size_t)b << 10) + kq * 8;

        f32x4 aL[4] = {{0.f,0.f,0.f,0.f},{0.f,0.f,0.f,0.f},{0.f,0.f,0.f,0.f},{0.f,0.f,0.f,0.f}};
        f32x4 aH[4] = {{0.f,0.f,0.f,0.f},{0.f,0.f,0.f,0.f},{0.f,0.f,0.f,0.f},{0.f,0.f,0.f,0.f}};
        half8 bb[16];
        #pragma unroll
        for (int kk = 0; kk < 16; ++kk) bb[kk] = *(const half8*)(bp + kk * 32);
        #pragma unroll
        for (int kk = 0; kk < 16; ++kk) {
            aL[kk & 3] = __builtin_amdgcn_mfma_f32_16x16x32_f16(wl[kk], bb[kk], aL[kk & 3], 0, 0, 0);
            aH[kk & 3] = __builtin_amdgcn_mfma_f32_16x16x32_f16(wh[kk], bb[kk], aH[kk & 3], 0, 0, 0);
        }
        #pragma unroll
        for (int kk = 0; kk < 16; ++kk) bb[kk] = *(const half8*)(bp + 512 + kk * 32);
        #pragma unroll
        for (int kk = 0; kk < 16; ++kk) {
            aL[kk & 3] = __builtin_amdgcn_mfma_f32_16x16x32_f16(wl[kk + 16], bb[kk], aL[kk & 3], 0, 0, 0);
            aH[kk & 3] = __builtin_amdgcn_mfma_f32_16x16x32_f16(wh[kk + 16], bb[kk], aH[kk & 3], 0, 0, 0);
        }

        f32x4 g4 = ((aL[0] + aL[1]) + (aL[2] + aL[3])) + ((aH[0] + aH[1]) + (aH[2] + aH[3]));

        const float* pt = pre2 + (size_t)tt * (4 * BH_) + ((size_t)b << 10) + j;
        const float gi = g4[0] + pt[0];
        const float gf = g4[1] + pt[BH_];
        const float gg = g4[2] + pt[2 * BH_];
        const float go = g4[3] + pt[3 * BH_];

        const float si = sigm(gi);
        const float sf = sigm(gf);
        const float tg = tanhf(gg);
        const float so = sigm(go);

        creg = sf * creg + si * tg;
        const float h = so * tanhf(creg);

        const size_t tbj = (size_t)t * BH_ + bj;
        hA[tbj] = h;
        if (hB) hB[tbj] = h;
        if (cO) cO[tbj] = creg;
        if (t < T_STEPS - 1) {
            _Float16* hnxt = hm + (size_t)((t + 1) & 1) * BH_;
            hnxt[bj] = (_Float16)(h * maskL[(size_t)(t + 1) * BH_ + bj]);
        }
    }
    cbuf[bj] = creg;
}

// ---------------------------------------------------------------------------
extern "C" void kernel_launch(void* const* d_in, const int* in_sizes, int n_in,
                              void* d_out, int out_size, void* d_ws, size_t ws_size,
                              hipStream_t stream)
{
    const float* x       = (const float*)d_in[0];
    const float* W_ih    = (const float*)d_in[1];
    const float* W_hh    = (const float*)d_in[2];
    const float* b_ih    = (const float*)d_in[3];
    const float* b_hh    = (const float*)d_in[4];
    const float* mask_h  = (const float*)d_in[5];
    const float* mask_in = (const float*)d_in[6];

    float* out0 = (float*)d_out;            // h_seq (layer 1)
    float* out1 = out0 + (size_t)OUTSZ;     // h_seq dup; layer-0 h_seq staging
    float* out2 = out0 + 2 * (size_t)OUTSZ; // c_seq (layer 1)

    char* ws = (char*)d_ws;
    size_t off = 0;
    auto alloc = [&](size_t bytes) { void* p = ws + off; off += (bytes + 255) & ~(size_t)255; return p; };

    const size_t WELEM = (size_t)2 * G4 * HID;  // elems per split array (both layers)
    _Float16* wih_hi = (_Float16*)alloc(WELEM * 2);
    _Float16* wih_lo = (_Float16*)alloc(WELEM * 2);
    _Float16* whh_hi = (_Float16*)alloc(WELEM * 2);
    _Float16* whh_lo = (_Float16*)alloc(WELEM * 2);
    float*    pre    = (float*)alloc((size_t)64 * BATCH * G4 * 4);   // 67 MB
    _Float16* hm     = (_Float16*)alloc((size_t)2 * BH_ * 2);        // 256 KB
    float*    cbuf   = (float*)alloc((size_t)BH_ * 4);               // 256 KB (adjacent to hm!)
    unsigned int* bar = (unsigned int*)alloc(4096);
    (void)ws_size; (void)in_sizes; (void)n_in; (void)out_size;

    split_w<<<8192, 256, 0, stream>>>(W_ih, W_hh, wih_hi, wih_lo, whh_hi, whh_lo);
    zero_ws<<<2, 256, 0, stream>>>((float*)bar, 512);   // barrier counters

    for (int l = 0; l < 2; ++l) {
        // zero hm ping-pong (256 KB) + cbuf (256 KB), contiguous = 131072 f32
        zero_ws<<<512, 256, 0, stream>>>((float*)hm, 131072);

        const float* Ain = l ? out1 : x;
        const float* Am  = l ? mask_in : nullptr;
        const _Float16* BH = wih_hi + (size_t)l * G4 * HID;
        const _Float16* BL = wih_lo + (size_t)l * G4 * HID;
        const _Float16* WH = whh_hi + (size_t)l * G4 * HID;
        const _Float16* WL = whh_lo + (size_t)l * G4 * HID;
        const float* bi = b_ih + l * G4;
        const float* bh = b_hh + l * G4;
        const float* maskL = mask_h + (size_t)l * OUTSZ;

        float* hA = l ? out0 : out1;
        float* hB = l ? out1 : nullptr;
        float* cO = l ? out2 : nullptr;

        for (int c = 0; c < 4; ++c) {
            pre_gemm<<<dim3(32, 32), 256, 0, stream>>>(Ain, Am, c * 4096, BH, BL, bi, bh, pre);
            scan_chunk<<<256, 256, 0, stream>>>(pre, WH, WL, hm, maskL, cbuf,
                                                hA, hB, cO,
                                                c * 64, (l * 4 + c) * 63, bar);
        }
    }
}

// Round 3
// 16222.252 us; speedup vs baseline: 1.3048x; 1.3048x over previous
//
#include <hip/hip_runtime.h>

// ---------------------------------------------------------------------------
// VariationalDropoutLSTM  (T=256, B=64, H=1024, L=2, fp32 in/out)
// Round 3: persistent scan, K-split across waves so Whh hi/lo is genuinely
// register-resident (64 VGPR/lane), LDS cross-wave reduction, XCD-blocked
// j-ownership, prefetched pre/mask, tree barrier with per-group release.
// ---------------------------------------------------------------------------

#define T_STEPS 256
#define BATCH   64
#define HID     1024
#define G4      4096
#define OUTSZ   (T_STEPS * BATCH * HID)   // 16777216
#define BH_     65536                      // BATCH*HID

typedef _Float16 half8 __attribute__((ext_vector_type(8)));
typedef _Float16 half4 __attribute__((ext_vector_type(4)));
typedef float    f32x4 __attribute__((ext_vector_type(4)));

__device__ __forceinline__ float fexp(float x) { return __expf(x); }
__device__ __forceinline__ float sigm(float x) {
    return __builtin_amdgcn_rcpf(1.0f + __expf(-x));
}
__device__ __forceinline__ float ftanh(float x) {
    float xc = fminf(15.0f, fmaxf(-15.0f, x));
    float a = __expf(2.0f * xc);
    return (a - 1.0f) * __builtin_amdgcn_rcpf(a + 1.0f);
}

// ---------------------------------------------------------------------------
__global__ __launch_bounds__(256) void zero_ws(float* p, int n) {
    int i = blockIdx.x * 256 + threadIdx.x;
    if (i < n) p[i] = 0.0f;
}

__global__ __launch_bounds__(256) void split_w(
    const float* __restrict__ wih, const float* __restrict__ whh,
    _Float16* __restrict__ wih_hi, _Float16* __restrict__ wih_lo,
    _Float16* __restrict__ whh_hi, _Float16* __restrict__ whh_lo)
{
    int i = blockIdx.x * 256 + threadIdx.x;
    {
        float4 a = ((const float4*)wih)[i];
        half4 h, l;
        h[0] = (_Float16)a.x; l[0] = (_Float16)(a.x - (float)h[0]);
        h[1] = (_Float16)a.y; l[1] = (_Float16)(a.y - (float)h[1]);
        h[2] = (_Float16)a.z; l[2] = (_Float16)(a.z - (float)h[2]);
        h[3] = (_Float16)a.w; l[3] = (_Float16)(a.w - (float)h[3]);
        ((half4*)wih_hi)[i] = h; ((half4*)wih_lo)[i] = l;
    }
    {
        float4 a = ((const float4*)whh)[i];
        half4 h, l;
        h[0] = (_Float16)a.x; l[0] = (_Float16)(a.x - (float)h[0]);
        h[1] = (_Float16)a.y; l[1] = (_Float16)(a.y - (float)h[1]);
        h[2] = (_Float16)a.z; l[2] = (_Float16)(a.z - (float)h[2]);
        h[3] = (_Float16)a.w; l[3] = (_Float16)(a.w - (float)h[3]);
        ((half4*)whh_hi)[i] = h; ((half4*)whh_lo)[i] = l;
    }
}

// ---------------------------------------------------------------------------
// pre_gemm: unchanged from round 2 (validated). pre2[tt][gate][b][j].
__global__ __launch_bounds__(256) void pre_gemm(
    const float* __restrict__ A, const float* __restrict__ Amask, int row0,
    const _Float16* __restrict__ Bhi, const _Float16* __restrict__ Blo,
    const float* __restrict__ bih, const float* __restrict__ bhh,
    float* __restrict__ preOut)
{
    __shared__ _Float16 As [128][40];
    __shared__ _Float16 BsH[128][40];
    __shared__ _Float16 BsL[128][40];

    const int bm = blockIdx.x, bn = blockIdx.y;
    const int tid = threadIdx.x;
    const int wave = tid >> 6, lane = tid & 63;
    const int wm = wave & 1, wn = wave >> 1;
    const int lr = lane & 15, kq = lane >> 4;

    f32x4 acc[4][4] = {};

    const int mrow = tid >> 3;
    const int k4   = (tid & 7) * 4;
    const int nrow = tid >> 1;
    const int kb   = (tid & 1) * 16;

    for (int kk = 0; kk < 32; ++kk) {
        const int k0 = kk * 32;
        #pragma unroll
        for (int mi = 0; mi < 4; ++mi) {
            const int m = mrow + mi * 32;
            const size_t gofs = (size_t)(row0 + bm * 128 + m) * 1024 + k0 + k4;
            float4 av = *(const float4*)(A + gofs);
            if (Amask) {
                float4 mv = *(const float4*)(Amask + gofs);
                av.x *= mv.x; av.y *= mv.y; av.z *= mv.z; av.w *= mv.w;
            }
            half4 hv;
            hv[0] = (_Float16)av.x; hv[1] = (_Float16)av.y;
            hv[2] = (_Float16)av.z; hv[3] = (_Float16)av.w;
            *(half4*)&As[m][k4] = hv;
        }
        {
            const size_t gofs = (size_t)(bn * 128 + nrow) * 1024 + k0 + kb;
            half8 b0 = *(const half8*)(Bhi + gofs);
            half8 b1 = *(const half8*)(Bhi + gofs + 8);
            *(half8*)&BsH[nrow][kb]     = b0;
            *(half8*)&BsH[nrow][kb + 8] = b1;
            half8 c0 = *(const half8*)(Blo + gofs);
            half8 c1 = *(const half8*)(Blo + gofs + 8);
            *(half8*)&BsL[nrow][kb]     = c0;
            *(half8*)&BsL[nrow][kb + 8] = c1;
        }
        __syncthreads();

        half8 af[4], bh[4], bl[4];
        #pragma unroll
        for (int i = 0; i < 4; ++i)
            af[i] = *(const half8*)&As[wm * 64 + i * 16 + lr][kq * 8];
        #pragma unroll
        for (int j = 0; j < 4; ++j) {
            bh[j] = *(const half8*)&BsH[wn * 64 + j * 16 + lr][kq * 8];
            bl[j] = *(const half8*)&BsL[wn * 64 + j * 16 + lr][kq * 8];
        }
        #pragma unroll
        for (int i = 0; i < 4; ++i)
            #pragma unroll
            for (int j = 0; j < 4; ++j) {
                acc[i][j] = __builtin_amdgcn_mfma_f32_16x16x32_f16(af[i], bl[j], acc[i][j], 0, 0, 0);
                acc[i][j] = __builtin_amdgcn_mfma_f32_16x16x32_f16(af[i], bh[j], acc[i][j], 0, 0, 0);
            }
        __syncthreads();
    }

    #pragma unroll
    for (int j4 = 0; j4 < 4; ++j4) {
        const int g = bn * 128 + wn * 64 + j4 * 16 + lr;
        const int gate = g >> 10, jc = g & 1023;
        const float bias = bih[g] + bhh[g];
        #pragma unroll
        for (int i = 0; i < 4; ++i) {
            const int rbase = bm * 128 + wm * 64 + i * 16 + kq * 4;
            #pragma unroll
            for (int r = 0; r < 4; ++r) {
                const int rloc = rbase + r;
                preOut[((size_t)(rloc >> 6) * 4 + gate) * BH_ + ((rloc & 63) << 10) + jc]
                    = acc[i][j4][r] + bias;
            }
        }
    }
}

// ---------------------------------------------------------------------------
// Grid barrier: tree arrival (8 groups of 32) + per-group release flags.
// bar layout (uint32 idx): group ctr g at [g*16]; root at [128];
// release flag g at [160+g*16].
__device__ __forceinline__ void grid_barrier(unsigned int* bar, int wg,
                                             unsigned int phase1) {
    __builtin_amdgcn_fence(__ATOMIC_RELEASE, "agent");
    __syncthreads();
    if (threadIdx.x == 0) {
        const int g = wg & 7;
        unsigned int old = __hip_atomic_fetch_add(&bar[g * 16], 1u,
                              __ATOMIC_ACQ_REL, __HIP_MEMORY_SCOPE_AGENT);
        if (old == 32u * phase1 - 1u) {
            unsigned int r = __hip_atomic_fetch_add(&bar[128], 1u,
                                __ATOMIC_ACQ_REL, __HIP_MEMORY_SCOPE_AGENT);
            if (r == 8u * phase1 - 1u) {
                #pragma unroll
                for (int gg = 0; gg < 8; ++gg)
                    __hip_atomic_store(&bar[160 + gg * 16], phase1,
                        __ATOMIC_RELEASE, __HIP_MEMORY_SCOPE_AGENT);
            }
        }
        while (__hip_atomic_load(&bar[160 + g * 16], __ATOMIC_RELAXED,
                                 __HIP_MEMORY_SCOPE_AGENT) < phase1)
            __builtin_amdgcn_s_sleep(1);
    }
    __syncthreads();
    __builtin_amdgcn_fence(__ATOMIC_ACQUIRE, "agent");
}

// ---------------------------------------------------------------------------
// Persistent scan, 64 steps/launch. 256 WGs x 256 thr.
// WG owns 4 hidden cols (XCD-blocked). Wave w owns K-slice [w*256,(w+1)*256):
// weights 16 half8 = 64 VGPR/lane, partial gate sums reduced via LDS.
__global__ __launch_bounds__(256) void scan_chunk(
    const float*    __restrict__ pre2,    // [64][4][64][1024]
    const _Float16* __restrict__ WhhHi,   // [4096][1024]
    const _Float16* __restrict__ WhhLo,
    _Float16*       __restrict__ hm,      // [2][64][1024] ping-pong
    const float*    __restrict__ maskL,   // mask_h layer base [256][64][1024]
    float*          __restrict__ cbuf,    // [64][1024]
    float*          __restrict__ hA,
    float*          __restrict__ hB,      // dup or null
    float*          __restrict__ cO,      // c out or null
    int tBase, int phaseBase63,
    unsigned int*   __restrict__ bar)
{
    __shared__ float red[4][16][66];      // [wave][row16][batch64+pad]

    const int wg   = blockIdx.x;
    const int jblk = (wg & 7) * 32 + (wg >> 3);  // XCD-blocked j ownership
    const int j0   = jblk << 2;
    const int tid  = threadIdx.x;
    const int w    = tid >> 6;            // wave = K-slice
    const int lane = tid & 63;
    const int lr   = lane & 15;
    const int kq   = lane >> 4;

    // A-frag row lr: gate = lr&3, jj = lr>>2  (local row = jj*4+gate)
    const int grow = (lr & 3) * HID + j0 + (lr >> 2);

    half8 wh[8], wl[8];
    {
        const _Float16* whp = WhhHi + (size_t)grow * HID + w * 256 + kq * 8;
        const _Float16* wlp = WhhLo + (size_t)grow * HID + w * 256 + kq * 8;
        #pragma unroll
        for (int kb = 0; kb < 8; ++kb) {
            wh[kb] = *(const half8*)(whp + kb * 32);
            wl[kb] = *(const half8*)(wlp + kb * 32);
        }
    }

    // elementwise mapping: b = w*16+lr, j = j0+kq
    const int b  = (w << 4) + lr;
    const int j  = j0 + kq;
    const size_t bj = (size_t)b * HID + j;

    float creg = cbuf[bj];

    // prefetch pre/mask for tt=0
    float pg0, pg1, pg2, pg3, pm;
    {
        const float* pt = pre2 + ((size_t)b << 10) + j;
        pg0 = pt[0]; pg1 = pt[BH_]; pg2 = pt[2 * BH_]; pg3 = pt[3 * BH_];
        pm = (tBase < T_STEPS - 1) ? maskL[(size_t)(tBase + 1) * BH_ + bj] : 0.0f;
    }

    #pragma unroll 1
    for (int tt = 0; tt < 64; ++tt) {
        const int t = tBase + tt;
        if (tt > 0) grid_barrier(bar, wg, (unsigned int)(phaseBase63 + tt));

        // ---- recurrent GEMM partial: rows 16 x batch 64, K-slice w ----
        const _Float16* hc = hm + (size_t)(t & 1) * BH_;
        f32x4 aH[4] = {{0,0,0,0},{0,0,0,0},{0,0,0,0},{0,0,0,0}};
        f32x4 aL[4] = {{0,0,0,0},{0,0,0,0},{0,0,0,0},{0,0,0,0}};
        #pragma unroll
        for (int bt = 0; bt < 4; ++bt) {
            const _Float16* bp = hc + ((size_t)(bt * 16 + lr) << 10) + w * 256 + kq * 8;
            half8 bb[8];
            #pragma unroll
            for (int kb = 0; kb < 8; ++kb) bb[kb] = *(const half8*)(bp + kb * 32);
            #pragma unroll
            for (int kb = 0; kb < 8; ++kb) {
                aL[bt] = __builtin_amdgcn_mfma_f32_16x16x32_f16(wl[kb], bb[kb], aL[bt], 0, 0, 0);
                aH[bt] = __builtin_amdgcn_mfma_f32_16x16x32_f16(wh[kb], bb[kb], aH[bt], 0, 0, 0);
            }
        }
        // partials -> LDS  (D: row = kq*4+r, col = bt*16+lr)
        #pragma unroll
        for (int bt = 0; bt < 4; ++bt) {
            f32x4 s = aH[bt] + aL[bt];
            #pragma unroll
            for (int r = 0; r < 4; ++r)
                red[w][kq * 4 + r][bt * 16 + lr] = s[r];
        }
        __syncthreads();

        // ---- reduce across waves + elementwise for (b, j) ----
        float gi = pg0, gf = pg1, gg = pg2, go = pg3;
        #pragma unroll
        for (int ww = 0; ww < 4; ++ww) {
            gi += red[ww][kq * 4 + 0][b & 63];
            gf += red[ww][kq * 4 + 1][b & 63];
            gg += red[ww][kq * 4 + 2][b & 63];
            go += red[ww][kq * 4 + 3][b & 63];
        }

        const float si = sigm(gi);
        const float sf = sigm(gf);
        const float tg = ftanh(gg);
        const float so = sigm(go);

        creg = sf * creg + si * tg;
        const float h = so * ftanh(creg);

        const size_t tbj = (size_t)t * BH_ + bj;
        hA[tbj] = h;
        if (hB) hB[tbj] = h;
        if (cO) cO[tbj] = creg;
        if (t < T_STEPS - 1)
            hm[(size_t)((t + 1) & 1) * BH_ + bj] = (_Float16)(h * pm);

        // prefetch next step's pre/mask (absorbed by barrier wait)
        if (tt < 63) {
            const float* pt = pre2 + (size_t)(tt + 1) * (4 * BH_) + ((size_t)b << 10) + j;
            pg0 = pt[0]; pg1 = pt[BH_]; pg2 = pt[2 * BH_]; pg3 = pt[3 * BH_];
            pm = (t + 1 < T_STEPS - 1) ? maskL[(size_t)(t + 2) * BH_ + bj] : 0.0f;
        }
    }
    cbuf[bj] = creg;
}

// ---------------------------------------------------------------------------
extern "C" void kernel_launch(void* const* d_in, const int* in_sizes, int n_in,
                              void* d_out, int out_size, void* d_ws, size_t ws_size,
                              hipStream_t stream)
{
    const float* x       = (const float*)d_in[0];
    const float* W_ih    = (const float*)d_in[1];
    const float* W_hh    = (const float*)d_in[2];
    const float* b_ih    = (const float*)d_in[3];
    const float* b_hh    = (const float*)d_in[4];
    const float* mask_h  = (const float*)d_in[5];
    const float* mask_in = (const float*)d_in[6];

    float* out0 = (float*)d_out;            // h_seq (layer 1)
    float* out1 = out0 + (size_t)OUTSZ;     // h_seq dup; layer-0 h_seq staging
    float* out2 = out0 + 2 * (size_t)OUTSZ; // c_seq (layer 1)

    char* ws = (char*)d_ws;
    size_t off = 0;
    auto alloc = [&](size_t bytes) { void* p = ws + off; off += (bytes + 255) & ~(size_t)255; return p; };

    const size_t WELEM = (size_t)2 * G4 * HID;
    _Float16* wih_hi = (_Float16*)alloc(WELEM * 2);
    _Float16* wih_lo = (_Float16*)alloc(WELEM * 2);
    _Float16* whh_hi = (_Float16*)alloc(WELEM * 2);
    _Float16* whh_lo = (_Float16*)alloc(WELEM * 2);
    float*    pre    = (float*)alloc((size_t)64 * BATCH * G4 * 4);   // 67 MB
    _Float16* hm     = (_Float16*)alloc((size_t)2 * BH_ * 2);        // 256 KB
    float*    cbuf   = (float*)alloc((size_t)BH_ * 4);               // 256 KB
    unsigned int* bar = (unsigned int*)alloc(4096);
    (void)ws_size; (void)in_sizes; (void)n_in; (void)out_size;

    split_w<<<8192, 256, 0, stream>>>(W_ih, W_hh, wih_hi, wih_lo, whh_hi, whh_lo);
    zero_ws<<<2, 256, 0, stream>>>((float*)bar, 512);

    for (int l = 0; l < 2; ++l) {
        zero_ws<<<512, 256, 0, stream>>>((float*)hm, 131072);  // hm + cbuf

        const float* Ain = l ? out1 : x;
        const float* Am  = l ? mask_in : nullptr;
        const _Float16* BH = wih_hi + (size_t)l * G4 * HID;
        const _Float16* BL = wih_lo + (size_t)l * G4 * HID;
        const _Float16* WH = whh_hi + (size_t)l * G4 * HID;
        const _Float16* WL = whh_lo + (size_t)l * G4 * HID;
        const float* bi = b_ih + l * G4;
        const float* bh = b_hh + l * G4;
        const float* maskL = mask_h + (size_t)l * OUTSZ;

        float* hA = l ? out0 : out1;
        float* hB = l ? out1 : nullptr;
        float* cO = l ? out2 : nullptr;

        for (int c = 0; c < 4; ++c) {
            pre_gemm<<<dim3(32, 32), 256, 0, stream>>>(Ain, Am, c * 4096, BH, BL, bi, bh, pre);
            scan_chunk<<<256, 256, 0, stream>>>(pre, WH, WL, hm, maskL, cbuf,
                                                hA, hB, cO,
                                                c * 64, (l * 4 + c) * 63, bar);
        }
    }
}